// Round 11
// baseline (343.725 us; speedup 1.0000x reference)
//
#include <hip/hip_runtime.h>
#include <hip/hip_fp16.h>

// ---------------------------------------------------------------------------
// DummyFairGCN R11: R10 + fully-predicated gather edge loop (no serial tail).
// 2-slice column gather (L2-resident halves), 2 edges x 32 cols, 16-edge
// predicated unroll = 8 outstanding loads EVERY iteration incl. tail.
// ---------------------------------------------------------------------------

typedef _Float16 f16x8 __attribute__((ext_vector_type(8)));
typedef float f32x4 __attribute__((ext_vector_type(4)));

static inline int cdiv(int a, int b) { return (a + b - 1) / b; }

__global__ __launch_bounds__(256) void k_zero_int(int* p, int n) {
    int i = blockIdx.x * 256 + threadIdx.x;
    if (i < n) p[i] = 0;
}

// ---- Pass A: per-block bucket histogram; reserve contiguous ranges ----
__global__ __launch_bounds__(256) void k_bcount(const int* __restrict__ ei, int E,
                                                int* bucketCount, int* blockBase) {
    __shared__ int lh[256];
    lh[threadIdx.x] = 0;
    __syncthreads();
    int base = blockIdx.x * 2048;
#pragma unroll
    for (int i = 0; i < 8; ++i) {
        int e = base + i * 256 + threadIdx.x;
        if (e < E) atomicAdd(&lh[ei[E + e] >> 8], 1);
    }
    __syncthreads();
    blockBase[blockIdx.x * 256 + threadIdx.x] =
        atomicAdd(&bucketCount[threadIdx.x], lh[threadIdx.x]);
}

// ---- bucket exclusive scan (single block); also rowptr[N]=E ----
__global__ void k_bscan(const int* __restrict__ bucketCount, int* bucketPtr, int nbk,
                        int* rowptr, int N, int E) {
    __shared__ int s[1024];
    int v = (threadIdx.x < nbk) ? bucketCount[threadIdx.x] : 0;
    s[threadIdx.x] = v;
    __syncthreads();
    for (int off = 1; off < 1024; off <<= 1) {
        int t = (threadIdx.x >= (unsigned)off) ? s[threadIdx.x - off] : 0;
        __syncthreads();
        s[threadIdx.x] += t;
        __syncthreads();
    }
    if (threadIdx.x < nbk) bucketPtr[threadIdx.x] = s[threadIdx.x] - v;
    if (threadIdx.x == 0) {
        bucketPtr[nbk] = E;
        rowptr[N] = E;
    }
}

// ---- Pass B: scatter edges into bucket-ordered ebuf (contiguous runs) ----
__global__ __launch_bounds__(256) void k_bscatter(const int* __restrict__ ei, int E,
                                                  const int* __restrict__ bucketPtr,
                                                  const int* __restrict__ blockBase,
                                                  int2* __restrict__ ebuf) {
    __shared__ int lh[256];
    lh[threadIdx.x] = 0;
    __syncthreads();
    int base = blockIdx.x * 2048;
    const int* bb = &blockBase[blockIdx.x * 256];
#pragma unroll
    for (int i = 0; i < 8; ++i) {
        int e = base + i * 256 + threadIdx.x;
        if (e < E) {
            int src = ei[e];
            int dst = ei[E + e];
            int b = dst >> 8;
            int lp = atomicAdd(&lh[b], 1);
            ebuf[bucketPtr[b] + bb[b] + lp] = int2{src, dst};
        }
    }
}

// ---- Pass C: per-bucket counting sort -> csr, rowptr, dinv ----
__global__ __launch_bounds__(256) void k_bcsr(const int2* __restrict__ ebuf,
                                              const int* __restrict__ bucketPtr,
                                              int* __restrict__ rowptr, float* __restrict__ dinv,
                                              int* __restrict__ csr, int N) {
    __shared__ int hist[256], excl[256], cur[256];
    const int b = blockIdx.x;
    const int base = bucketPtr[b];
    const int cnt = bucketPtr[b + 1] - base;
    const int t = threadIdx.x;
    hist[t] = 0;
    cur[t] = 0;
    __syncthreads();
    for (int i = t; i < cnt; i += 256) atomicAdd(&hist[ebuf[base + i].y & 255], 1);
    __syncthreads();
    int v = hist[t];
    excl[t] = v;
    __syncthreads();
    for (int off = 1; off < 256; off <<= 1) {
        int x = (t >= off) ? excl[t - off] : 0;
        __syncthreads();
        excl[t] += x;
        __syncthreads();
    }
    int ex = excl[t] - v;
    int node = b * 256 + t;
    if (node < N) {
        rowptr[node] = base + ex;
        dinv[node] = rsqrtf((float)(v + 1));  // +1 self-loop
    }
    __syncthreads();
    excl[t] = ex;
    __syncthreads();
    for (int i = t; i < cnt; i += 256) {
        int2 e = ebuf[base + i];
        int ln = e.y & 255;
        int pos = base + excl[ln] + atomicAdd(&cur[ln], 1);
        csr[pos] = e.x;
    }
}

// ---- fused prep: x->fp16 row-major XH + all 5 weight transposes ----
__device__ inline bool wt_job(int i, int lo, int hi, int K, int FO, const float* W, __half* T) {
    if (i < lo || i >= hi) return false;
    int j = i - lo;
    int c = j / K;
    int k = j - c * K;
    T[j] = (c < FO) ? __float2half_rn(W[(size_t)k * FO + c]) : __half(0.f);
    return true;
}

__global__ __launch_bounds__(256) void k_prep(const float* __restrict__ x, __half* __restrict__ XH,
                                              int nf,  // N*32 float4-groups
                                              const float* w1, const float* w2, const float* w3,
                                              const float* w4, const float* w5, __half* t1,
                                              __half* t2, __half* t3, __half* t4, __half* t5) {
    int i = blockIdx.x * 256 + threadIdx.x;
    if (i < nf) {
        float4 v = ((const float4*)x)[i];
        __half h[4] = {__float2half_rn(v.x), __float2half_rn(v.y), __float2half_rn(v.z),
                       __float2half_rn(v.w)};
        ((uint2*)XH)[i] = *(uint2*)h;
        return;
    }
    int j = i - nf;
    if (wt_job(j, 0, 16384, 128, 128, w1, t1)) return;
    if (wt_job(j, 16384, 32768, 128, 128, w2, t2)) return;
    if (wt_job(j, 32768, 65536, 128, 256, w3, t3)) return;
    if (wt_job(j, 65536, 98304, 256, 128, w4, t4)) return;
    wt_job(j, 98304, 106496, 128, 40, w5, t5);
}

// ---------------------------------------------------------------------------
// 2-pass column-sliced CSR gather, FULLY PREDICATED edge loop.
// Slice s reads bytes [s*64B, s*64B+128B) of each 256B row.
// Wave = 1 node; lanes = 2 edges (lane>>5) x 32 half2-cols (lane&31).
// Every 16-edge iteration issues 8 csr + 8 dinv + 8 data loads (OOB edges
// clamped to p1-1 with zero weight) -> no serial tail.
// ---------------------------------------------------------------------------
__global__ __launch_bounds__(256) void k_gather2(const int* __restrict__ rowptr,
                                                 const int* __restrict__ csr,
                                                 const float* __restrict__ dinv,
                                                 const __half* __restrict__ xh,
                                                 __half* __restrict__ G, int N, int BPS) {
    int blk = blockIdx.x;
    int s = blk / BPS;  // slice 0/1 (dispatch-order sequenced)
    int nb = blk - s * BPS;
    int node = nb * 4 + (threadIdx.x >> 6);
    if (node >= N) return;
    int lane = threadIdx.x & 63;
    int half = lane >> 5;
    int c = lane & 31;
    const __half2* xs = (const __half2*)xh;  // row stride 64 half2
    const int cofs = s * 32 + c;
    float di = dinv[node];
    int p0 = rowptr[node], p1 = rowptr[node + 1];
    float ax = 0.f, ay = 0.f;
    for (int p = p0; p < p1; p += 16) {
        int s_[8];
        float wg[8];
        __half2 v[8];
#pragma unroll
        for (int j = 0; j < 8; ++j) {
            int idx = p + 2 * j + half;
            bool ok = idx < p1;
            s_[j] = csr[ok ? idx : p1 - 1];
            wg[j] = ok ? dinv[s_[j]] : 0.f;
        }
#pragma unroll
        for (int j = 0; j < 8; ++j) v[j] = xs[(size_t)s_[j] * 64 + cofs];
#pragma unroll
        for (int j = 0; j < 8; ++j) {
            float2 f = __half22float2(v[j]);
            ax += wg[j] * f.x;
            ay += wg[j] * f.y;
        }
    }
    ax += __shfl_xor(ax, 32, 64);
    ay += __shfl_xor(ay, 32, 64);
    if (half == 0) {
        float2 f = __half22float2(xs[(size_t)node * 64 + cofs]);
        ax = di * (ax + di * f.x);
        ay = di * (ay + di * f.y);
        ((__half2*)G)[(size_t)node * 64 + cofs] = __floats2half2_rn(ax, ay);
    }
}

// ---------------------------------------------------------------------------
// MFMA fp16 GEMM, fused epilogue (BN+ReLU / bias+ReLU / bias).
// Block = 4 waves; tile 128 rows x 64 cols; wave = 32x64.
// C/D: col=lane&15, row=(lane>>4)*4+reg  [HW-verified m89/m91].
// ncols masks bias load + stores (for FO=40 padded to 64).
// ---------------------------------------------------------------------------
template <int K, bool BN, bool RELU, typename OT>
__global__ __launch_bounds__(256) void k_mfma(const __half* __restrict__ A,
                                              const __half* __restrict__ Wt,
                                              const float* __restrict__ cb,
                                              const float* __restrict__ g,
                                              const float* __restrict__ bb,
                                              const float* __restrict__ m,
                                              const float* __restrict__ vv,
                                              OT* __restrict__ Y, int ldy, int N, int ncols) {
    constexpr int KS = K / 32;
    constexpr int NCT = 4;  // 64 cols
    __shared__ __half bs[KS * NCT * 64 * 8];

    const int tid = threadIdx.x;
    const int col0 = blockIdx.y * 64;

    constexpr int PIECES = KS * NCT * 64;
#pragma unroll
    for (int p = tid; p < PIECES; p += 256) {
        int ks = p / (NCT * 64);
        int rem = p - ks * (NCT * 64);
        int ct = rem >> 6;
        int l = rem & 63;
        int col = col0 + ct * 16 + (l & 15);
        int kg = ks * 32 + (l >> 4) * 8;
        *(uint4*)&bs[p * 8] = *(const uint4*)&Wt[(size_t)col * K + kg];
    }
    __syncthreads();

    const int wave = tid >> 6;
    const int lane = tid & 63;
    const int rbase = blockIdx.x * 128 + wave * 32;
    const int r0 = rbase + (lane & 15);
    const int k0 = (lane >> 4) * 8;

    uint4 af[2][KS];
#pragma unroll
    for (int ks = 0; ks < KS; ++ks) {
        int kk = ks * 32 + k0;
        af[0][ks] = (r0 < N) ? *(const uint4*)&A[(size_t)r0 * K + kk] : uint4{0, 0, 0, 0};
        af[1][ks] = (r0 + 16 < N) ? *(const uint4*)&A[(size_t)(r0 + 16) * K + kk]
                                  : uint4{0, 0, 0, 0};
    }

    f32x4 acc[2][NCT];
#pragma unroll
    for (int rt = 0; rt < 2; ++rt)
#pragma unroll
        for (int ct = 0; ct < NCT; ++ct) acc[rt][ct] = {0.f, 0.f, 0.f, 0.f};

#pragma unroll
    for (int ks = 0; ks < KS; ++ks) {
        f16x8 b[NCT];
#pragma unroll
        for (int ct = 0; ct < NCT; ++ct)
            b[ct] = *(const f16x8*)&bs[((ks * NCT + ct) * 64 + lane) * 8];
#pragma unroll
        for (int rt = 0; rt < 2; ++rt) {
            f16x8 a = *(const f16x8*)&af[rt][ks];
#pragma unroll
            for (int ct = 0; ct < NCT; ++ct)
                acc[rt][ct] = __builtin_amdgcn_mfma_f32_16x16x32_f16(a, b[ct], acc[rt][ct], 0, 0, 0);
        }
    }

    const int cbase = col0 + (lane & 15);
#pragma unroll
    for (int ct = 0; ct < NCT; ++ct) {
        int col = cbase + ct * 16;
        if (col >= ncols) continue;
        float sc, sh;
        if (BN) {
            sc = g[col] * rsqrtf(vv[col] + 1e-5f);
            sh = bb[col] + (cb[col] - m[col]) * sc;
        } else {
            sc = 1.f;
            sh = cb[col];
        }
#pragma unroll
        for (int rt = 0; rt < 2; ++rt) {
#pragma unroll
            for (int r = 0; r < 4; ++r) {
                int row = rbase + rt * 16 + (lane >> 4) * 4 + r;
                if (row < N) {
                    float o = acc[rt][ct][r] * sc + sh;
                    if (RELU) o = fmaxf(o, 0.f);
                    if constexpr (sizeof(OT) == 2) {
                        Y[(size_t)row * ldy + col] = __float2half_rn(o);
                    } else {
                        Y[(size_t)row * ldy + col] = o;
                    }
                }
            }
        }
    }
}

extern "C" void kernel_launch(void* const* d_in, const int* in_sizes, int n_in,
                              void* d_out, int out_size, void* d_ws, size_t ws_size,
                              hipStream_t stream) {
    const float* x = (const float*)d_in[0];
    const int* ei = (const int*)d_in[1];
    const float* cw1 = (const float*)d_in[2];
    const float* cb1 = (const float*)d_in[3];
    const float* g1 = (const float*)d_in[4];
    const float* bb1 = (const float*)d_in[5];
    const float* m1 = (const float*)d_in[6];
    const float* v1 = (const float*)d_in[7];
    const float* cw2 = (const float*)d_in[8];
    const float* cb2 = (const float*)d_in[9];
    const float* g2 = (const float*)d_in[10];
    const float* bb2 = (const float*)d_in[11];
    const float* m2 = (const float*)d_in[12];
    const float* v2 = (const float*)d_in[13];
    const float* cw3 = (const float*)d_in[14];
    const float* cb3 = (const float*)d_in[15];
    const float* g3 = (const float*)d_in[16];
    const float* bb3 = (const float*)d_in[17];
    const float* m3 = (const float*)d_in[18];
    const float* v3 = (const float*)d_in[19];
    const float* lw1 = (const float*)d_in[20];
    const float* lb1 = (const float*)d_in[21];
    const float* lw2 = (const float*)d_in[22];
    const float* lb2 = (const float*)d_in[23];
    float* out = (float*)d_out;

    const int N = in_sizes[0] / 128;
    const int E = in_sizes[1] / 2;
    const int NBK = cdiv(N, 256);   // dst buckets of 256 nodes
    const int NBA = cdiv(E, 2048);  // pass A/B blocks
    const int BPS = cdiv(N, 4);     // gather blocks per slice

    auto al = [](size_t v) { return (v + 255) & ~(size_t)255; };
    char* w = (char*)d_ws;
    size_t o = 0;
    float* dinv  = (float*)(w + o);  o = al(o + (size_t)N * 4);
    int* rowptr  = (int*)(w + o);    o = al(o + (size_t)(N + 1) * 4);
    int* bcount  = (int*)(w + o);    o = al(o + 256 * 4);
    int* bptr    = (int*)(w + o);    o = al(o + (256 + 1) * 4);
    int* bbase   = (int*)(w + o);    o = al(o + (size_t)NBA * 256 * 4);
    int2* ebuf   = (int2*)(w + o);   o = al(o + (size_t)E * 8);
    int* csr     = (int*)(w + o);    o = al(o + (size_t)E * 4);
    __half* XH   = (__half*)(w + o); o = al(o + (size_t)N * 128 * 2);
    __half* GH   = (__half*)(w + o); o = al(o + (size_t)N * 128 * 2);
    __half* H3h  = (__half*)(w + o); o = al(o + (size_t)N * 256 * 2);
    __half* Wt1  = (__half*)(w + o); o = al(o + (size_t)128 * 128 * 2);
    __half* Wt2  = (__half*)(w + o); o = al(o + (size_t)128 * 128 * 2);
    __half* Wt3  = (__half*)(w + o); o = al(o + (size_t)256 * 128 * 2);
    __half* Wt4  = (__half*)(w + o); o = al(o + (size_t)128 * 256 * 2);
    __half* Wt5  = (__half*)(w + o); o = al(o + (size_t)64 * 128 * 2);
    __half* Zh   = GH;  // lin1 output overlays GH (dead after conv3 GEMM)

    // ---- CSR build (bucketed counting sort) ----
    k_zero_int<<<1, 256, 0, stream>>>(bcount, 256);
    k_bcount<<<NBA, 256, 0, stream>>>(ei, E, bcount, bbase);
    k_bscan<<<1, 1024, 0, stream>>>(bcount, bptr, NBK, rowptr, N, E);
    k_bscatter<<<NBA, 256, 0, stream>>>(ei, E, bptr, bbase, ebuf);
    k_bcsr<<<NBK, 256, 0, stream>>>(ebuf, bptr, rowptr, dinv, csr, N);

    // ---- fused conversions ----
    k_prep<<<cdiv(N * 32 + 106496, 256), 256, 0, stream>>>(x, XH, N * 32, cw1, cw2, cw3, lw1,
                                                           lw2, Wt1, Wt2, Wt3, Wt4, Wt5);

    const int gx = cdiv(N, 128);

    // ---- conv1
    k_gather2<<<2 * BPS, 256, 0, stream>>>(rowptr, csr, dinv, XH, GH, N, BPS);
    k_mfma<128, true, true, __half><<<dim3(gx, 2), 256, 0, stream>>>(
        GH, Wt1, cb1, g1, bb1, m1, v1, XH, 128, N, 128);
    // ---- conv2
    k_gather2<<<2 * BPS, 256, 0, stream>>>(rowptr, csr, dinv, XH, GH, N, BPS);
    k_mfma<128, true, true, __half><<<dim3(gx, 2), 256, 0, stream>>>(
        GH, Wt2, cb2, g2, bb2, m2, v2, XH, 128, N, 128);
    // ---- conv3 (FO=256)
    k_gather2<<<2 * BPS, 256, 0, stream>>>(rowptr, csr, dinv, XH, GH, N, BPS);
    k_mfma<128, true, true, __half><<<dim3(gx, 4), 256, 0, stream>>>(
        GH, Wt3, cb3, g3, bb3, m3, v3, H3h, 256, N, 256);
    // ---- lin1: Zh = relu(H3h @ lw1 + lb1)
    k_mfma<256, false, true, __half><<<dim3(gx, 2), 256, 0, stream>>>(
        H3h, Wt4, lb1, nullptr, nullptr, nullptr, nullptr, Zh, 128, N, 128);
    // ---- lin2: out = Zh @ lw2 + lb2 (fp32, 40 cols)
    k_mfma<128, false, false, float><<<dim3(gx, 1), 256, 0, stream>>>(
        Zh, Wt5, lb2, nullptr, nullptr, nullptr, nullptr, out, 40, N, 40);
}

// Round 12
// 227.882 us; speedup vs baseline: 1.5083x; 1.5083x over previous
//
#include <hip/hip_runtime.h>
#include <hip/hip_fp16.h>

// ---------------------------------------------------------------------------
// DummyFairGCN R12: revert gather to R8's k_gather64 (row-major XH, 64 lanes
// per node, 8-edge unroll) — slicing experiments R9-R11 all regressed (gather
// is latency/issue-bound, not L2-miss-bound). Keep fused prep. Pack ebuf to
// 4B/edge (src | dstLow<<24) to halve CSR-build traffic.
// ---------------------------------------------------------------------------

typedef _Float16 f16x8 __attribute__((ext_vector_type(8)));
typedef float f32x4 __attribute__((ext_vector_type(4)));

static inline int cdiv(int a, int b) { return (a + b - 1) / b; }

__global__ __launch_bounds__(256) void k_zero_int(int* p, int n) {
    int i = blockIdx.x * 256 + threadIdx.x;
    if (i < n) p[i] = 0;
}

// ---- Pass A: per-block bucket histogram; reserve contiguous ranges ----
__global__ __launch_bounds__(256) void k_bcount(const int* __restrict__ ei, int E,
                                                int* bucketCount, int* blockBase) {
    __shared__ int lh[256];
    lh[threadIdx.x] = 0;
    __syncthreads();
    int base = blockIdx.x * 2048;
#pragma unroll
    for (int i = 0; i < 8; ++i) {
        int e = base + i * 256 + threadIdx.x;
        if (e < E) atomicAdd(&lh[ei[E + e] >> 8], 1);
    }
    __syncthreads();
    blockBase[blockIdx.x * 256 + threadIdx.x] =
        atomicAdd(&bucketCount[threadIdx.x], lh[threadIdx.x]);
}

// ---- bucket exclusive scan (single block); also rowptr[N]=E ----
__global__ void k_bscan(const int* __restrict__ bucketCount, int* bucketPtr, int nbk,
                        int* rowptr, int N, int E) {
    __shared__ int s[1024];
    int v = (threadIdx.x < nbk) ? bucketCount[threadIdx.x] : 0;
    s[threadIdx.x] = v;
    __syncthreads();
    for (int off = 1; off < 1024; off <<= 1) {
        int t = (threadIdx.x >= (unsigned)off) ? s[threadIdx.x - off] : 0;
        __syncthreads();
        s[threadIdx.x] += t;
        __syncthreads();
    }
    if (threadIdx.x < nbk) bucketPtr[threadIdx.x] = s[threadIdx.x] - v;
    if (threadIdx.x == 0) {
        bucketPtr[nbk] = E;
        rowptr[N] = E;
    }
}

// ---- Pass B: scatter packed edges into bucket-ordered ebuf ----
// pack: src (24 bits, N < 2^24) | (dst & 255) << 24
__global__ __launch_bounds__(256) void k_bscatter(const int* __restrict__ ei, int E,
                                                  const int* __restrict__ bucketPtr,
                                                  const int* __restrict__ blockBase,
                                                  unsigned int* __restrict__ ebuf) {
    __shared__ int lh[256];
    lh[threadIdx.x] = 0;
    __syncthreads();
    int base = blockIdx.x * 2048;
    const int* bb = &blockBase[blockIdx.x * 256];
#pragma unroll
    for (int i = 0; i < 8; ++i) {
        int e = base + i * 256 + threadIdx.x;
        if (e < E) {
            unsigned int src = (unsigned int)ei[e];
            unsigned int dst = (unsigned int)ei[E + e];
            int b = dst >> 8;
            int lp = atomicAdd(&lh[b], 1);
            ebuf[bucketPtr[b] + bb[b] + lp] = src | ((dst & 255u) << 24);
        }
    }
}

// ---- Pass C: per-bucket counting sort -> csr, rowptr, dinv ----
__global__ __launch_bounds__(256) void k_bcsr(const unsigned int* __restrict__ ebuf,
                                              const int* __restrict__ bucketPtr,
                                              int* __restrict__ rowptr, float* __restrict__ dinv,
                                              int* __restrict__ csr, int N) {
    __shared__ int hist[256], excl[256], cur[256];
    const int b = blockIdx.x;
    const int base = bucketPtr[b];
    const int cnt = bucketPtr[b + 1] - base;
    const int t = threadIdx.x;
    hist[t] = 0;
    cur[t] = 0;
    __syncthreads();
    for (int i = t; i < cnt; i += 256) atomicAdd(&hist[ebuf[base + i] >> 24], 1);
    __syncthreads();
    int v = hist[t];
    excl[t] = v;
    __syncthreads();
    for (int off = 1; off < 256; off <<= 1) {
        int x = (t >= off) ? excl[t - off] : 0;
        __syncthreads();
        excl[t] += x;
        __syncthreads();
    }
    int ex = excl[t] - v;
    int node = b * 256 + t;
    if (node < N) {
        rowptr[node] = base + ex;
        dinv[node] = rsqrtf((float)(v + 1));  // +1 self-loop
    }
    __syncthreads();
    excl[t] = ex;
    __syncthreads();
    for (int i = t; i < cnt; i += 256) {
        unsigned int e = ebuf[base + i];
        int ln = e >> 24;
        int pos = base + excl[ln] + atomicAdd(&cur[ln], 1);
        csr[pos] = (int)(e & 0xFFFFFFu);
    }
}

// ---- fused prep: x->fp16 row-major XH + all 5 weight transposes ----
__device__ inline bool wt_job(int i, int lo, int hi, int K, int FO, const float* W, __half* T) {
    if (i < lo || i >= hi) return false;
    int j = i - lo;
    int c = j / K;
    int k = j - c * K;
    T[j] = (c < FO) ? __float2half_rn(W[(size_t)k * FO + c]) : __half(0.f);
    return true;
}

__global__ __launch_bounds__(256) void k_prep(const float* __restrict__ x, __half* __restrict__ XH,
                                              int nf,  // N*32 float4-groups
                                              const float* w1, const float* w2, const float* w3,
                                              const float* w4, const float* w5, __half* t1,
                                              __half* t2, __half* t3, __half* t4, __half* t5) {
    int i = blockIdx.x * 256 + threadIdx.x;
    if (i < nf) {
        float4 v = ((const float4*)x)[i];
        __half h[4] = {__float2half_rn(v.x), __float2half_rn(v.y), __float2half_rn(v.z),
                       __float2half_rn(v.w)};
        ((uint2*)XH)[i] = *(uint2*)h;
        return;
    }
    int j = i - nf;
    if (wt_job(j, 0, 16384, 128, 128, w1, t1)) return;
    if (wt_job(j, 16384, 32768, 128, 128, w2, t2)) return;
    if (wt_job(j, 32768, 65536, 128, 256, w3, t3)) return;
    if (wt_job(j, 65536, 98304, 256, 128, w4, t4)) return;
    wt_job(j, 98304, 106496, 128, 40, w5, t5);
}

// CSR gather over 128-wide fp16 rows -> fp16 out (fp32 accum).  [R8 winner]
// 64 lanes per node (one wave), 4B (__half2) per lane per edge, 8-edge unroll.
// csr/dinv loads are wave-uniform (scalar path); di factor hoisted.
__global__ __launch_bounds__(256) void k_gather64(const int* __restrict__ rowptr,
                                                  const int* __restrict__ csr,
                                                  const float* __restrict__ dinv,
                                                  const __half* __restrict__ xh,
                                                  __half* __restrict__ G, int N) {
    int t = blockIdx.x * 256 + threadIdx.x;
    int node = t >> 6;
    if (node >= N) return;
    int lane = t & 63;
    const __half2* xb = (const __half2*)xh;  // 64 half2 per row
    float di = dinv[node];
    float ax = 0.f, ay = 0.f;
    int p0 = rowptr[node], p1 = rowptr[node + 1];
    int p = p0;
    for (; p + 8 <= p1; p += 8) {
        int s_[8];
        float wg[8];
        __half2 v[8];
#pragma unroll
        for (int j = 0; j < 8; ++j) s_[j] = csr[p + j];
#pragma unroll
        for (int j = 0; j < 8; ++j) wg[j] = dinv[s_[j]];
#pragma unroll
        for (int j = 0; j < 8; ++j) v[j] = xb[(size_t)s_[j] * 64 + lane];
#pragma unroll
        for (int j = 0; j < 8; ++j) {
            float2 f = __half22float2(v[j]);
            ax += wg[j] * f.x;
            ay += wg[j] * f.y;
        }
    }
    for (; p + 4 <= p1; p += 4) {
        int s_[4];
        float wg[4];
        __half2 v[4];
#pragma unroll
        for (int j = 0; j < 4; ++j) s_[j] = csr[p + j];
#pragma unroll
        for (int j = 0; j < 4; ++j) wg[j] = dinv[s_[j]];
#pragma unroll
        for (int j = 0; j < 4; ++j) v[j] = xb[(size_t)s_[j] * 64 + lane];
#pragma unroll
        for (int j = 0; j < 4; ++j) {
            float2 f = __half22float2(v[j]);
            ax += wg[j] * f.x;
            ay += wg[j] * f.y;
        }
    }
    for (; p < p1; ++p) {
        int src = csr[p];
        float w = dinv[src];
        float2 f = __half22float2(xb[(size_t)src * 64 + lane]);
        ax += w * f.x;
        ay += w * f.y;
    }
    {
        float2 f = __half22float2(xb[(size_t)node * 64 + lane]);
        ax = di * (ax + di * f.x);
        ay = di * (ay + di * f.y);
    }
    ((__half2*)G)[(size_t)node * 64 + lane] = __floats2half2_rn(ax, ay);
}

// ---------------------------------------------------------------------------
// MFMA fp16 GEMM, fused epilogue (BN+ReLU / bias+ReLU / bias).
// Block = 4 waves; tile 128 rows x 64 cols; wave = 32x64.
// C/D: col=lane&15, row=(lane>>4)*4+reg  [HW-verified m89/m91].
// ncols masks bias load + stores (for FO=40 padded to 64).
// ---------------------------------------------------------------------------
template <int K, bool BN, bool RELU, typename OT>
__global__ __launch_bounds__(256) void k_mfma(const __half* __restrict__ A,
                                              const __half* __restrict__ Wt,
                                              const float* __restrict__ cb,
                                              const float* __restrict__ g,
                                              const float* __restrict__ bb,
                                              const float* __restrict__ m,
                                              const float* __restrict__ vv,
                                              OT* __restrict__ Y, int ldy, int N, int ncols) {
    constexpr int KS = K / 32;
    constexpr int NCT = 4;  // 64 cols
    __shared__ __half bs[KS * NCT * 64 * 8];

    const int tid = threadIdx.x;
    const int col0 = blockIdx.y * 64;

    constexpr int PIECES = KS * NCT * 64;
#pragma unroll
    for (int p = tid; p < PIECES; p += 256) {
        int ks = p / (NCT * 64);
        int rem = p - ks * (NCT * 64);
        int ct = rem >> 6;
        int l = rem & 63;
        int col = col0 + ct * 16 + (l & 15);
        int kg = ks * 32 + (l >> 4) * 8;
        *(uint4*)&bs[p * 8] = *(const uint4*)&Wt[(size_t)col * K + kg];
    }
    __syncthreads();

    const int wave = tid >> 6;
    const int lane = tid & 63;
    const int rbase = blockIdx.x * 128 + wave * 32;
    const int r0 = rbase + (lane & 15);
    const int k0 = (lane >> 4) * 8;

    uint4 af[2][KS];
#pragma unroll
    for (int ks = 0; ks < KS; ++ks) {
        int kk = ks * 32 + k0;
        af[0][ks] = (r0 < N) ? *(const uint4*)&A[(size_t)r0 * K + kk] : uint4{0, 0, 0, 0};
        af[1][ks] = (r0 + 16 < N) ? *(const uint4*)&A[(size_t)(r0 + 16) * K + kk]
                                  : uint4{0, 0, 0, 0};
    }

    f32x4 acc[2][NCT];
#pragma unroll
    for (int rt = 0; rt < 2; ++rt)
#pragma unroll
        for (int ct = 0; ct < NCT; ++ct) acc[rt][ct] = {0.f, 0.f, 0.f, 0.f};

#pragma unroll
    for (int ks = 0; ks < KS; ++ks) {
        f16x8 b[NCT];
#pragma unroll
        for (int ct = 0; ct < NCT; ++ct)
            b[ct] = *(const f16x8*)&bs[((ks * NCT + ct) * 64 + lane) * 8];
#pragma unroll
        for (int rt = 0; rt < 2; ++rt) {
            f16x8 a = *(const f16x8*)&af[rt][ks];
#pragma unroll
            for (int ct = 0; ct < NCT; ++ct)
                acc[rt][ct] = __builtin_amdgcn_mfma_f32_16x16x32_f16(a, b[ct], acc[rt][ct], 0, 0, 0);
        }
    }

    const int cbase = col0 + (lane & 15);
#pragma unroll
    for (int ct = 0; ct < NCT; ++ct) {
        int col = cbase + ct * 16;
        if (col >= ncols) continue;
        float sc, sh;
        if (BN) {
            sc = g[col] * rsqrtf(vv[col] + 1e-5f);
            sh = bb[col] + (cb[col] - m[col]) * sc;
        } else {
            sc = 1.f;
            sh = cb[col];
        }
#pragma unroll
        for (int rt = 0; rt < 2; ++rt) {
#pragma unroll
            for (int r = 0; r < 4; ++r) {
                int row = rbase + rt * 16 + (lane >> 4) * 4 + r;
                if (row < N) {
                    float o = acc[rt][ct][r] * sc + sh;
                    if (RELU) o = fmaxf(o, 0.f);
                    if constexpr (sizeof(OT) == 2) {
                        Y[(size_t)row * ldy + col] = __float2half_rn(o);
                    } else {
                        Y[(size_t)row * ldy + col] = o;
                    }
                }
            }
        }
    }
}

extern "C" void kernel_launch(void* const* d_in, const int* in_sizes, int n_in,
                              void* d_out, int out_size, void* d_ws, size_t ws_size,
                              hipStream_t stream) {
    const float* x = (const float*)d_in[0];
    const int* ei = (const int*)d_in[1];
    const float* cw1 = (const float*)d_in[2];
    const float* cb1 = (const float*)d_in[3];
    const float* g1 = (const float*)d_in[4];
    const float* bb1 = (const float*)d_in[5];
    const float* m1 = (const float*)d_in[6];
    const float* v1 = (const float*)d_in[7];
    const float* cw2 = (const float*)d_in[8];
    const float* cb2 = (const float*)d_in[9];
    const float* g2 = (const float*)d_in[10];
    const float* bb2 = (const float*)d_in[11];
    const float* m2 = (const float*)d_in[12];
    const float* v2 = (const float*)d_in[13];
    const float* cw3 = (const float*)d_in[14];
    const float* cb3 = (const float*)d_in[15];
    const float* g3 = (const float*)d_in[16];
    const float* bb3 = (const float*)d_in[17];
    const float* m3 = (const float*)d_in[18];
    const float* v3 = (const float*)d_in[19];
    const float* lw1 = (const float*)d_in[20];
    const float* lb1 = (const float*)d_in[21];
    const float* lw2 = (const float*)d_in[22];
    const float* lb2 = (const float*)d_in[23];
    float* out = (float*)d_out;

    const int N = in_sizes[0] / 128;
    const int E = in_sizes[1] / 2;
    const int NBK = cdiv(N, 256);   // dst buckets of 256 nodes
    const int NBA = cdiv(E, 2048);  // pass A/B blocks

    auto al = [](size_t v) { return (v + 255) & ~(size_t)255; };
    char* w = (char*)d_ws;
    size_t o = 0;
    float* dinv  = (float*)(w + o);  o = al(o + (size_t)N * 4);
    int* rowptr  = (int*)(w + o);    o = al(o + (size_t)(N + 1) * 4);
    int* bcount  = (int*)(w + o);    o = al(o + 256 * 4);
    int* bptr    = (int*)(w + o);    o = al(o + (256 + 1) * 4);
    int* bbase   = (int*)(w + o);    o = al(o + (size_t)NBA * 256 * 4);
    unsigned int* ebuf = (unsigned int*)(w + o); o = al(o + (size_t)E * 4);
    int* csr     = (int*)(w + o);    o = al(o + (size_t)E * 4);
    __half* XH   = (__half*)(w + o); o = al(o + (size_t)N * 128 * 2);
    __half* GH   = (__half*)(w + o); o = al(o + (size_t)N * 128 * 2);
    __half* H3h  = (__half*)(w + o); o = al(o + (size_t)N * 256 * 2);
    __half* Wt1  = (__half*)(w + o); o = al(o + (size_t)128 * 128 * 2);
    __half* Wt2  = (__half*)(w + o); o = al(o + (size_t)128 * 128 * 2);
    __half* Wt3  = (__half*)(w + o); o = al(o + (size_t)256 * 128 * 2);
    __half* Wt4  = (__half*)(w + o); o = al(o + (size_t)128 * 256 * 2);
    __half* Wt5  = (__half*)(w + o); o = al(o + (size_t)64 * 128 * 2);
    __half* Zh   = GH;  // lin1 output overlays GH (dead after conv3 GEMM)

    // ---- CSR build (bucketed counting sort, packed edges) ----
    k_zero_int<<<1, 256, 0, stream>>>(bcount, 256);
    k_bcount<<<NBA, 256, 0, stream>>>(ei, E, bcount, bbase);
    k_bscan<<<1, 1024, 0, stream>>>(bcount, bptr, NBK, rowptr, N, E);
    k_bscatter<<<NBA, 256, 0, stream>>>(ei, E, bptr, bbase, ebuf);
    k_bcsr<<<NBK, 256, 0, stream>>>(ebuf, bptr, rowptr, dinv, csr, N);

    // ---- fused conversions ----
    k_prep<<<cdiv(N * 32 + 106496, 256), 256, 0, stream>>>(x, XH, N * 32, cw1, cw2, cw3, lw1,
                                                           lw2, Wt1, Wt2, Wt3, Wt4, Wt5);

    const int gx = cdiv(N, 128);

    // ---- conv1
    k_gather64<<<cdiv(N, 4), 256, 0, stream>>>(rowptr, csr, dinv, XH, GH, N);
    k_mfma<128, true, true, __half><<<dim3(gx, 2), 256, 0, stream>>>(
        GH, Wt1, cb1, g1, bb1, m1, v1, XH, 128, N, 128);
    // ---- conv2
    k_gather64<<<cdiv(N, 4), 256, 0, stream>>>(rowptr, csr, dinv, XH, GH, N);
    k_mfma<128, true, true, __half><<<dim3(gx, 2), 256, 0, stream>>>(
        GH, Wt2, cb2, g2, bb2, m2, v2, XH, 128, N, 128);
    // ---- conv3 (FO=256)
    k_gather64<<<cdiv(N, 4), 256, 0, stream>>>(rowptr, csr, dinv, XH, GH, N);
    k_mfma<128, true, true, __half><<<dim3(gx, 4), 256, 0, stream>>>(
        GH, Wt3, cb3, g3, bb3, m3, v3, H3h, 256, N, 256);
    // ---- lin1: Zh = relu(H3h @ lw1 + lb1)
    k_mfma<256, false, true, __half><<<dim3(gx, 2), 256, 0, stream>>>(
        H3h, Wt4, lb1, nullptr, nullptr, nullptr, nullptr, Zh, 128, N, 128);
    // ---- lin2: out = Zh @ lw2 + lb2 (fp32, 40 cols)
    k_mfma<128, false, false, float><<<dim3(gx, 1), 256, 0, stream>>>(
        Zh, Wt5, lb2, nullptr, nullptr, nullptr, nullptr, out, 40, N, 40);
}

// Round 13
// 222.838 us; speedup vs baseline: 1.5425x; 1.0226x over previous
//
#include <hip/hip_runtime.h>
#include <hip/hip_fp16.h>

// ---------------------------------------------------------------------------
// DummyFairGCN R13: R12 hot path bit-identical; launch-count trims only.
//  - memsetAsync(bcount) replaces k_zero_int
//  - in-block 256-scan inside bscatter/bcsr replaces k_bscan (1-block kernel)
//  - prep merged into bcount launch (disjoint block ranges)
// 14 dispatches -> 11 (+1 tiny memset).
// ---------------------------------------------------------------------------

typedef _Float16 f16x8 __attribute__((ext_vector_type(8)));
typedef float f32x4 __attribute__((ext_vector_type(4)));

static inline int cdiv(int a, int b) { return (a + b - 1) / b; }

// ---- fused front: blocks [0,NBA) do bucket histogram; rest do prep ----
__device__ inline bool wt_job(int i, int lo, int hi, int K, int FO, const float* W, __half* T) {
    if (i < lo || i >= hi) return false;
    int j = i - lo;
    int c = j / K;
    int k = j - c * K;
    T[j] = (c < FO) ? __float2half_rn(W[(size_t)k * FO + c]) : __half(0.f);
    return true;
}

__global__ __launch_bounds__(256) void k_front(const int* __restrict__ ei, int E, int NBA,
                                               int* bucketCount, int* blockBase,
                                               const float* __restrict__ x,
                                               __half* __restrict__ XH, int nf,
                                               const float* w1, const float* w2, const float* w3,
                                               const float* w4, const float* w5, __half* t1,
                                               __half* t2, __half* t3, __half* t4, __half* t5) {
    __shared__ int lh[256];
    if ((int)blockIdx.x < NBA) {
        // bucket histogram + per-block base reservation
        lh[threadIdx.x] = 0;
        __syncthreads();
        int base = blockIdx.x * 2048;
#pragma unroll
        for (int i = 0; i < 8; ++i) {
            int e = base + i * 256 + threadIdx.x;
            if (e < E) atomicAdd(&lh[ei[E + e] >> 8], 1);
        }
        __syncthreads();
        blockBase[blockIdx.x * 256 + threadIdx.x] =
            atomicAdd(&bucketCount[threadIdx.x], lh[threadIdx.x]);
        return;
    }
    // prep: x->fp16 XH + 5 weight transposes
    int i = (blockIdx.x - NBA) * 256 + threadIdx.x;
    if (i < nf) {
        float4 v = ((const float4*)x)[i];
        __half h[4] = {__float2half_rn(v.x), __float2half_rn(v.y), __float2half_rn(v.z),
                       __float2half_rn(v.w)};
        ((uint2*)XH)[i] = *(uint2*)h;
        return;
    }
    int j = i - nf;
    if (wt_job(j, 0, 16384, 128, 128, w1, t1)) return;
    if (wt_job(j, 16384, 32768, 128, 128, w2, t2)) return;
    if (wt_job(j, 32768, 65536, 128, 256, w3, t3)) return;
    if (wt_job(j, 65536, 98304, 256, 128, w4, t4)) return;
    wt_job(j, 98304, 106496, 128, 40, w5, t5);
}

// ---- Pass B: scatter packed edges into bucket-ordered ebuf ----
// pack: src (24 bits, N < 2^24) | (dst & 255) << 24. In-block scan of bcount.
__global__ __launch_bounds__(256) void k_bscatter(const int* __restrict__ ei, int E,
                                                  const int* __restrict__ bcount,
                                                  const int* __restrict__ blockBase,
                                                  unsigned int* __restrict__ ebuf) {
    __shared__ int sc[256];
    __shared__ int bp[256];
    __shared__ int lh[256];
    const int t = threadIdx.x;
    int v = bcount[t];
    sc[t] = v;
    __syncthreads();
    for (int off = 1; off < 256; off <<= 1) {
        int x = (t >= off) ? sc[t - off] : 0;
        __syncthreads();
        sc[t] += x;
        __syncthreads();
    }
    bp[t] = sc[t] - v;  // exclusive bucket base
    lh[t] = 0;
    __syncthreads();
    int base = blockIdx.x * 2048;
    const int* bb = &blockBase[blockIdx.x * 256];
#pragma unroll
    for (int i = 0; i < 8; ++i) {
        int e = base + i * 256 + t;
        if (e < E) {
            unsigned int src = (unsigned int)ei[e];
            unsigned int dst = (unsigned int)ei[E + e];
            int b = dst >> 8;
            int lp = atomicAdd(&lh[b], 1);
            ebuf[bp[b] + bb[b] + lp] = src | ((dst & 255u) << 24);
        }
    }
}

// ---- Pass C: per-bucket counting sort -> csr, rowptr, dinv ----
// In-block scan of bcount gives this bucket's [base, base+cnt).
__global__ __launch_bounds__(256) void k_bcsr(const unsigned int* __restrict__ ebuf,
                                              const int* __restrict__ bcount,
                                              int* __restrict__ rowptr, float* __restrict__ dinv,
                                              int* __restrict__ csr, int N, int E) {
    __shared__ int sc[256];
    __shared__ int hist[256], excl[256], cur[256];
    const int b = blockIdx.x;
    const int t = threadIdx.x;
    int bv = bcount[t];
    sc[t] = bv;
    __syncthreads();
    for (int off = 1; off < 256; off <<= 1) {
        int x = (t >= off) ? sc[t - off] : 0;
        __syncthreads();
        sc[t] += x;
        __syncthreads();
    }
    const int cnt = bcount[b];           // uniform scalar load
    const int base = sc[b] - cnt;        // exclusive base of bucket b
    if (b == (int)gridDim.x - 1 && t == 0) rowptr[N] = E;
    hist[t] = 0;
    cur[t] = 0;
    __syncthreads();
    for (int i = t; i < cnt; i += 256) atomicAdd(&hist[ebuf[base + i] >> 24], 1);
    __syncthreads();
    int v = hist[t];
    excl[t] = v;
    __syncthreads();
    for (int off = 1; off < 256; off <<= 1) {
        int x = (t >= off) ? excl[t - off] : 0;
        __syncthreads();
        excl[t] += x;
        __syncthreads();
    }
    int ex = excl[t] - v;
    int node = b * 256 + t;
    if (node < N) {
        rowptr[node] = base + ex;
        dinv[node] = rsqrtf((float)(v + 1));  // +1 self-loop
    }
    __syncthreads();
    excl[t] = ex;
    __syncthreads();
    for (int i = t; i < cnt; i += 256) {
        unsigned int e = ebuf[base + i];
        int ln = e >> 24;
        int pos = base + excl[ln] + atomicAdd(&cur[ln], 1);
        csr[pos] = (int)(e & 0xFFFFFFu);
    }
}

// CSR gather over 128-wide fp16 rows -> fp16 out (fp32 accum).  [R8 winner]
// 64 lanes per node (one wave), 4B (__half2) per lane per edge, 8-edge unroll.
__global__ __launch_bounds__(256) void k_gather64(const int* __restrict__ rowptr,
                                                  const int* __restrict__ csr,
                                                  const float* __restrict__ dinv,
                                                  const __half* __restrict__ xh,
                                                  __half* __restrict__ G, int N) {
    int t = blockIdx.x * 256 + threadIdx.x;
    int node = t >> 6;
    if (node >= N) return;
    int lane = t & 63;
    const __half2* xb = (const __half2*)xh;  // 64 half2 per row
    float di = dinv[node];
    float ax = 0.f, ay = 0.f;
    int p0 = rowptr[node], p1 = rowptr[node + 1];
    int p = p0;
    for (; p + 8 <= p1; p += 8) {
        int s_[8];
        float wg[8];
        __half2 v[8];
#pragma unroll
        for (int j = 0; j < 8; ++j) s_[j] = csr[p + j];
#pragma unroll
        for (int j = 0; j < 8; ++j) wg[j] = dinv[s_[j]];
#pragma unroll
        for (int j = 0; j < 8; ++j) v[j] = xb[(size_t)s_[j] * 64 + lane];
#pragma unroll
        for (int j = 0; j < 8; ++j) {
            float2 f = __half22float2(v[j]);
            ax += wg[j] * f.x;
            ay += wg[j] * f.y;
        }
    }
    for (; p + 4 <= p1; p += 4) {
        int s_[4];
        float wg[4];
        __half2 v[4];
#pragma unroll
        for (int j = 0; j < 4; ++j) s_[j] = csr[p + j];
#pragma unroll
        for (int j = 0; j < 4; ++j) wg[j] = dinv[s_[j]];
#pragma unroll
        for (int j = 0; j < 4; ++j) v[j] = xb[(size_t)s_[j] * 64 + lane];
#pragma unroll
        for (int j = 0; j < 4; ++j) {
            float2 f = __half22float2(v[j]);
            ax += wg[j] * f.x;
            ay += wg[j] * f.y;
        }
    }
    for (; p < p1; ++p) {
        int src = csr[p];
        float w = dinv[src];
        float2 f = __half22float2(xb[(size_t)src * 64 + lane]);
        ax += w * f.x;
        ay += w * f.y;
    }
    {
        float2 f = __half22float2(xb[(size_t)node * 64 + lane]);
        ax = di * (ax + di * f.x);
        ay = di * (ay + di * f.y);
    }
    ((__half2*)G)[(size_t)node * 64 + lane] = __floats2half2_rn(ax, ay);
}

// ---------------------------------------------------------------------------
// MFMA fp16 GEMM, fused epilogue (BN+ReLU / bias+ReLU / bias).
// Block = 4 waves; tile 128 rows x 64 cols; wave = 32x64.
// C/D: col=lane&15, row=(lane>>4)*4+reg  [HW-verified m89/m91].
// ncols masks bias load + stores (for FO=40 padded to 64).
// ---------------------------------------------------------------------------
template <int K, bool BN, bool RELU, typename OT>
__global__ __launch_bounds__(256) void k_mfma(const __half* __restrict__ A,
                                              const __half* __restrict__ Wt,
                                              const float* __restrict__ cb,
                                              const float* __restrict__ g,
                                              const float* __restrict__ bb,
                                              const float* __restrict__ m,
                                              const float* __restrict__ vv,
                                              OT* __restrict__ Y, int ldy, int N, int ncols) {
    constexpr int KS = K / 32;
    constexpr int NCT = 4;  // 64 cols
    __shared__ __half bs[KS * NCT * 64 * 8];

    const int tid = threadIdx.x;
    const int col0 = blockIdx.y * 64;

    constexpr int PIECES = KS * NCT * 64;
#pragma unroll
    for (int p = tid; p < PIECES; p += 256) {
        int ks = p / (NCT * 64);
        int rem = p - ks * (NCT * 64);
        int ct = rem >> 6;
        int l = rem & 63;
        int col = col0 + ct * 16 + (l & 15);
        int kg = ks * 32 + (l >> 4) * 8;
        *(uint4*)&bs[p * 8] = *(const uint4*)&Wt[(size_t)col * K + kg];
    }
    __syncthreads();

    const int wave = tid >> 6;
    const int lane = tid & 63;
    const int rbase = blockIdx.x * 128 + wave * 32;
    const int r0 = rbase + (lane & 15);
    const int k0 = (lane >> 4) * 8;

    uint4 af[2][KS];
#pragma unroll
    for (int ks = 0; ks < KS; ++ks) {
        int kk = ks * 32 + k0;
        af[0][ks] = (r0 < N) ? *(const uint4*)&A[(size_t)r0 * K + kk] : uint4{0, 0, 0, 0};
        af[1][ks] = (r0 + 16 < N) ? *(const uint4*)&A[(size_t)(r0 + 16) * K + kk]
                                  : uint4{0, 0, 0, 0};
    }

    f32x4 acc[2][NCT];
#pragma unroll
    for (int rt = 0; rt < 2; ++rt)
#pragma unroll
        for (int ct = 0; ct < NCT; ++ct) acc[rt][ct] = {0.f, 0.f, 0.f, 0.f};

#pragma unroll
    for (int ks = 0; ks < KS; ++ks) {
        f16x8 b[NCT];
#pragma unroll
        for (int ct = 0; ct < NCT; ++ct)
            b[ct] = *(const f16x8*)&bs[((ks * NCT + ct) * 64 + lane) * 8];
#pragma unroll
        for (int rt = 0; rt < 2; ++rt) {
            f16x8 a = *(const f16x8*)&af[rt][ks];
#pragma unroll
            for (int ct = 0; ct < NCT; ++ct)
                acc[rt][ct] = __builtin_amdgcn_mfma_f32_16x16x32_f16(a, b[ct], acc[rt][ct], 0, 0, 0);
        }
    }

    const int cbase = col0 + (lane & 15);
#pragma unroll
    for (int ct = 0; ct < NCT; ++ct) {
        int col = cbase + ct * 16;
        if (col >= ncols) continue;
        float sc, sh;
        if (BN) {
            sc = g[col] * rsqrtf(vv[col] + 1e-5f);
            sh = bb[col] + (cb[col] - m[col]) * sc;
        } else {
            sc = 1.f;
            sh = cb[col];
        }
#pragma unroll
        for (int rt = 0; rt < 2; ++rt) {
#pragma unroll
            for (int r = 0; r < 4; ++r) {
                int row = rbase + rt * 16 + (lane >> 4) * 4 + r;
                if (row < N) {
                    float o = acc[rt][ct][r] * sc + sh;
                    if (RELU) o = fmaxf(o, 0.f);
                    if constexpr (sizeof(OT) == 2) {
                        Y[(size_t)row * ldy + col] = __float2half_rn(o);
                    } else {
                        Y[(size_t)row * ldy + col] = o;
                    }
                }
            }
        }
    }
}

extern "C" void kernel_launch(void* const* d_in, const int* in_sizes, int n_in,
                              void* d_out, int out_size, void* d_ws, size_t ws_size,
                              hipStream_t stream) {
    const float* x = (const float*)d_in[0];
    const int* ei = (const int*)d_in[1];
    const float* cw1 = (const float*)d_in[2];
    const float* cb1 = (const float*)d_in[3];
    const float* g1 = (const float*)d_in[4];
    const float* bb1 = (const float*)d_in[5];
    const float* m1 = (const float*)d_in[6];
    const float* v1 = (const float*)d_in[7];
    const float* cw2 = (const float*)d_in[8];
    const float* cb2 = (const float*)d_in[9];
    const float* g2 = (const float*)d_in[10];
    const float* bb2 = (const float*)d_in[11];
    const float* m2 = (const float*)d_in[12];
    const float* v2 = (const float*)d_in[13];
    const float* cw3 = (const float*)d_in[14];
    const float* cb3 = (const float*)d_in[15];
    const float* g3 = (const float*)d_in[16];
    const float* bb3 = (const float*)d_in[17];
    const float* m3 = (const float*)d_in[18];
    const float* v3 = (const float*)d_in[19];
    const float* lw1 = (const float*)d_in[20];
    const float* lb1 = (const float*)d_in[21];
    const float* lw2 = (const float*)d_in[22];
    const float* lb2 = (const float*)d_in[23];
    float* out = (float*)d_out;

    const int N = in_sizes[0] / 128;
    const int E = in_sizes[1] / 2;
    const int NBK = cdiv(N, 256);   // dst buckets of 256 nodes
    const int NBA = cdiv(E, 2048);  // histogram/scatter blocks

    auto al = [](size_t v) { return (v + 255) & ~(size_t)255; };
    char* w = (char*)d_ws;
    size_t o = 0;
    float* dinv  = (float*)(w + o);  o = al(o + (size_t)N * 4);
    int* rowptr  = (int*)(w + o);    o = al(o + (size_t)(N + 1) * 4);
    int* bcount  = (int*)(w + o);    o = al(o + 256 * 4);
    int* bbase   = (int*)(w + o);    o = al(o + (size_t)NBA * 256 * 4);
    unsigned int* ebuf = (unsigned int*)(w + o); o = al(o + (size_t)E * 4);
    int* csr     = (int*)(w + o);    o = al(o + (size_t)E * 4);
    __half* XH   = (__half*)(w + o); o = al(o + (size_t)N * 128 * 2);
    __half* GH   = (__half*)(w + o); o = al(o + (size_t)N * 128 * 2);
    __half* H3h  = (__half*)(w + o); o = al(o + (size_t)N * 256 * 2);
    __half* Wt1  = (__half*)(w + o); o = al(o + (size_t)128 * 128 * 2);
    __half* Wt2  = (__half*)(w + o); o = al(o + (size_t)128 * 128 * 2);
    __half* Wt3  = (__half*)(w + o); o = al(o + (size_t)256 * 128 * 2);
    __half* Wt4  = (__half*)(w + o); o = al(o + (size_t)128 * 256 * 2);
    __half* Wt5  = (__half*)(w + o); o = al(o + (size_t)64 * 128 * 2);
    __half* Zh   = GH;  // lin1 output overlays GH (dead after conv3 GEMM)

    // ---- front: histogram (blocks [0,NBA)) + prep (rest); bcount via memset ----
    hipMemsetAsync(bcount, 0, 256 * sizeof(int), stream);
    const int nf = N * 32;  // float4-groups in x
    const int prepBlocks = cdiv(nf + 106496, 256);
    k_front<<<NBA + prepBlocks, 256, 0, stream>>>(ei, E, NBA, bcount, bbase, x, XH, nf, cw1, cw2,
                                                  cw3, lw1, lw2, Wt1, Wt2, Wt3, Wt4, Wt5);
    // ---- CSR build (in-block scans; no separate bscan kernel) ----
    k_bscatter<<<NBA, 256, 0, stream>>>(ei, E, bcount, bbase, ebuf);
    k_bcsr<<<NBK, 256, 0, stream>>>(ebuf, bcount, rowptr, dinv, csr, N, E);

    const int gx = cdiv(N, 128);

    // ---- conv1
    k_gather64<<<cdiv(N, 4), 256, 0, stream>>>(rowptr, csr, dinv, XH, GH, N);
    k_mfma<128, true, true, __half><<<dim3(gx, 2), 256, 0, stream>>>(
        GH, Wt1, cb1, g1, bb1, m1, v1, XH, 128, N, 128);
    // ---- conv2
    k_gather64<<<cdiv(N, 4), 256, 0, stream>>>(rowptr, csr, dinv, XH, GH, N);
    k_mfma<128, true, true, __half><<<dim3(gx, 2), 256, 0, stream>>>(
        GH, Wt2, cb2, g2, bb2, m2, v2, XH, 128, N, 128);
    // ---- conv3 (FO=256)
    k_gather64<<<cdiv(N, 4), 256, 0, stream>>>(rowptr, csr, dinv, XH, GH, N);
    k_mfma<128, true, true, __half><<<dim3(gx, 4), 256, 0, stream>>>(
        GH, Wt3, cb3, g3, bb3, m3, v3, H3h, 256, N, 256);
    // ---- lin1: Zh = relu(H3h @ lw1 + lb1)
    k_mfma<256, false, true, __half><<<dim3(gx, 2), 256, 0, stream>>>(
        H3h, Wt4, lb1, nullptr, nullptr, nullptr, nullptr, Zh, 128, N, 128);
    // ---- lin2: out = Zh @ lw2 + lb2 (fp32, 40 cols)
    k_mfma<128, false, false, float><<<dim3(gx, 1), 256, 0, stream>>>(
        Zh, Wt5, lb2, nullptr, nullptr, nullptr, nullptr, out, 40, N, 40);
}